// Round 2
// baseline (200.205 us; speedup 1.0000x reference)
//
#include <hip/hip_runtime.h>
#include <math.h>

// z = (64,64,64,64) fp32 -> 262144 vectors of dim 64; codebook = 1024 x 64 fp32.
constexpr int DIM  = 64;
constexpr int KCB  = 1024;
constexpr int NVEC = 262144;
constexpr long long NELEM = 16777216LL;
constexpr int WAVES   = 16;              // 1024 threads/block
constexpr int ROWS_PB = 512;             // 32 rows per wave
constexpr int GRID    = NVEC / ROWS_PB;  // 512 blocks = 2 per CU (70 KB LDS)
constexpr int KHALF   = 512;             // codewords staged per half

typedef short bf16x8 __attribute__((ext_vector_type(8)));  // 8 bf16 = 4 VGPRs
typedef float f32x4  __attribute__((ext_vector_type(4)));

// async global->LDS, 16 B per lane; LDS dest = wave-uniform base + lane*16
#define GLDS16(gp, lp) __builtin_amdgcn_global_load_lds(                      \
    (const __attribute__((address_space(1))) unsigned int*)(gp),              \
    (__attribute__((address_space(3))) unsigned int*)(lp), 16, 0, 0)

// fp32 -> bf16 round-to-nearest-even
__device__ __forceinline__ unsigned f2bfu(float f) {
    union { float f; unsigned u; } v; v.f = f;
    return (v.u + 0x7fffu + ((v.u >> 16) & 1u)) >> 16;
}

// Prep: cbbf = bf16(-2*cb) row-major, esq = ||e_k||^2, zero ws[0..1].
__global__ __launch_bounds__(1024) void vq_prep(const float* __restrict__ cb,
        short* __restrict__ cbbf, float* __restrict__ esq, float* __restrict__ ws) {
    int i = blockIdx.x * 1024 + threadIdx.x;   // 64 blocks x 1024 = 65536
    cbbf[i] = (short)f2bfu(-2.0f * cb[i]);
    if (i < KCB) {
        const float* e = cb + i * DIM;
        float s0 = 0.f, s1 = 0.f, s2 = 0.f, s3 = 0.f;
        #pragma unroll
        for (int j = 0; j < DIM; j += 4) {
            float4 v = *(const float4*)(e + j);
            s0 = fmaf(v.x, v.x, s0);
            s1 = fmaf(v.y, v.y, s1);
            s2 = fmaf(v.z, v.z, s2);
            s3 = fmaf(v.w, v.w, s3);
        }
        esq[i] = (s0 + s1) + (s2 + s3);
    }
    if (i == 0) { ws[0] = 0.f; ((unsigned*)ws)[1] = 0u; }
}

// Main: fused argmin+gather+loss. Codebook staged in TWO 64 KB K-halves via
// global_load_lds width=16 (pre-swizzled source: 16-B unit `part` of codeword
// `col` at LDS slot col*8+((part+col)&7) -> ds_read_b128 fragments conflict-
// free). 70 KB LDS + <=64 VGPR => 2 blocks/CU, 8 waves/SIMD: one block's
// stage/barrier/store phases hide under the other block's hot loop.
__global__ __launch_bounds__(1024, 8) void vq_main(
        const float* __restrict__ z,
        const float* __restrict__ cb,
        const short* __restrict__ cbbf,
        const float* __restrict__ esq,
        float* __restrict__ out,
        float* __restrict__ ws) {

    __shared__ unsigned sB[KHALF * 32];     // 64 KB staged half-codebook
    __shared__ float    s_esq[KCB];         // 4 KB
    __shared__ int      s_idx[WAVES * 32];  // 2 KB per-wave argmin exchange
    __shared__ float    s_red[WAVES];       // block loss partials

    const int tid  = threadIdx.x;
    const int lane = tid & 63;
    const int wave = tid >> 6;
    const int quad = lane >> 4;
    const int lrow = lane & 15;
    const int r0   = blockIdx.x * ROWS_PB + wave * 32;

    // Staging geometry: slot s = wave*256 + j*64 + lane (j=0..3) over the
    // 4096 16-B units of a half. col = s>>3, pos = s&7, part = (pos-col)&7.
    unsigned gofs[4], lofs[4];
    #pragma unroll
    for (int j = 0; j < 4; ++j) {
        int s = wave * 256 + j * 64 + lane;
        int col = s >> 3, pos = s & 7;
        int part = (pos - col) & 7;
        gofs[j] = (unsigned)((col * 8 + part) * 16);
        lofs[j] = (unsigned)((wave * 256 + j * 64) * 16);
    }
    const char* gB = (const char*)cbbf;
    #pragma unroll
    for (int j = 0; j < 4; ++j)                      // half 0, fire-and-forget
        GLDS16(gB + gofs[j], (char*)sB + lofs[j]);

    s_esq[tid] = esq[tid];

    // A fragments: A[m=lane&15][k=quad*8+j], bf16(z); exact fp32 ||z||^2
    // partials (each lane covers 16 elems of its rows).
    bf16x8 a0[2], a1[2];
    float zsq = 0.f;
    #pragma unroll
    for (int t = 0; t < 2; ++t) {
        const float* zr = z + (size_t)(r0 + t * 16 + lrow) * DIM + quad * 8;
        float4 p0 = *(const float4*)(zr);
        float4 p1 = *(const float4*)(zr + 4);
        float4 p2 = *(const float4*)(zr + 32);
        float4 p3 = *(const float4*)(zr + 36);
        zsq = fmaf(p0.x, p0.x, zsq); zsq = fmaf(p0.y, p0.y, zsq);
        zsq = fmaf(p0.z, p0.z, zsq); zsq = fmaf(p0.w, p0.w, zsq);
        zsq = fmaf(p1.x, p1.x, zsq); zsq = fmaf(p1.y, p1.y, zsq);
        zsq = fmaf(p1.z, p1.z, zsq); zsq = fmaf(p1.w, p1.w, zsq);
        zsq = fmaf(p2.x, p2.x, zsq); zsq = fmaf(p2.y, p2.y, zsq);
        zsq = fmaf(p2.z, p2.z, zsq); zsq = fmaf(p2.w, p2.w, zsq);
        zsq = fmaf(p3.x, p3.x, zsq); zsq = fmaf(p3.y, p3.y, zsq);
        zsq = fmaf(p3.z, p3.z, zsq); zsq = fmaf(p3.w, p3.w, zsq);
        a0[t][0] = (short)f2bfu(p0.x); a0[t][1] = (short)f2bfu(p0.y);
        a0[t][2] = (short)f2bfu(p0.z); a0[t][3] = (short)f2bfu(p0.w);
        a0[t][4] = (short)f2bfu(p1.x); a0[t][5] = (short)f2bfu(p1.y);
        a0[t][6] = (short)f2bfu(p1.z); a0[t][7] = (short)f2bfu(p1.w);
        a1[t][0] = (short)f2bfu(p2.x); a1[t][1] = (short)f2bfu(p2.y);
        a1[t][2] = (short)f2bfu(p2.z); a1[t][3] = (short)f2bfu(p2.w);
        a1[t][4] = (short)f2bfu(p3.x); a1[t][5] = (short)f2bfu(p3.y);
        a1[t][6] = (short)f2bfu(p3.z); a1[t][7] = (short)f2bfu(p3.w);
    }

    __syncthreads();   // drains half-0 GLDS (vmcnt) + esq write

    float best[2][4];
    #pragma unroll
    for (int t = 0; t < 2; ++t)
        #pragma unroll
        for (int i = 0; i < 4; ++i) best[t][i] = INFINITY;

    const int pos0 = ((quad + lrow) & 7) * 4;       // b0: part=quad   (K 0..31)
    const int pos1 = ((quad + 4 + lrow) & 7) * 4;   // b1: part=quad+4 (K 32..63)

    for (int half = 0; half < 2; ++half) {
        const int kbase = half * KHALF;
        #pragma unroll 2
        for (int ks = 0; ks < 32; ks += 2) {
            const int row = ks * 16 + lrow;
            const unsigned* bpA = sB + row * 32;
            const unsigned* bpB = bpA + 512;         // codeword group row+16
            bf16x8 b0A = *(const bf16x8*)(bpA + pos0);
            bf16x8 b1A = *(const bf16x8*)(bpA + pos1);
            bf16x8 b0B = *(const bf16x8*)(bpB + pos0);
            bf16x8 b1B = *(const bf16x8*)(bpB + pos1);
            const float esA = s_esq[kbase + row];
            const float esB = s_esq[kbase + row + 16];
            const unsigned cvA = (unsigned)(kbase + row);
            const unsigned cvB = cvA + 16u;
            #pragma unroll
            for (int t = 0; t < 2; ++t) {
                f32x4 accA = { esA, esA, esA, esA };
                accA = __builtin_amdgcn_mfma_f32_16x16x32_bf16(a0[t], b0A, accA, 0, 0, 0);
                accA = __builtin_amdgcn_mfma_f32_16x16x32_bf16(a1[t], b1A, accA, 0, 0, 0);
                f32x4 accB = { esB, esB, esB, esB };
                accB = __builtin_amdgcn_mfma_f32_16x16x32_bf16(a0[t], b0B, accB, 0, 0, 0);
                accB = __builtin_amdgcn_mfma_f32_16x16x32_bf16(a1[t], b1B, accB, 0, 0, 0);
                #pragma unroll
                for (int i = 0; i < 4; ++i) {
                    unsigned uA = __float_as_uint(accA[i]);
                    unsigned uB = __float_as_uint(accB[i]);
                    float pkA = __uint_as_float((uA & 0xFFFFFC00u) | cvA);
                    float pkB = __uint_as_float((uB & 0xFFFFFC00u) | cvB);
                    best[t][i] = fminf(best[t][i], fminf(pkA, pkB));
                }
            }
        }
        if (half == 0) {
            __syncthreads();                         // all waves done reading
            #pragma unroll
            for (int j = 0; j < 4; ++j)              // stage half 1
                GLDS16(gB + KHALF * DIM * 2 + gofs[j], (char*)sB + lofs[j]);
            __syncthreads();                         // drains half-1 GLDS
        }
    }

    // min across the 16-lane col group (quad-local butterfly)
    #pragma unroll
    for (int t = 0; t < 2; ++t)
        #pragma unroll
        for (int i = 0; i < 4; ++i) {
            float bs = best[t][i];
            bs = fminf(bs, __shfl_xor(bs, 1, 64));
            bs = fminf(bs, __shfl_xor(bs, 2, 64));
            bs = fminf(bs, __shfl_xor(bs, 4, 64));
            bs = fminf(bs, __shfl_xor(bs, 8, 64));
            best[t][i] = bs;
        }

    // lane lrow = t*4+i (lrow<8) owns row t*16 + quad*4 + i (static select)
    float mypk = best[0][0];
    #pragma unroll
    for (int t = 0; t < 2; ++t)
        #pragma unroll
        for (int i = 0; i < 4; ++i)
            if (lrow == t * 4 + i) mypk = best[t][i];

    const unsigned ub = __float_as_uint(mypk);
    float lsum = zsq;
    if (lrow < 8) {
        s_idx[wave * 32 + (lrow >> 2) * 16 + quad * 4 + (lrow & 3)] =
            (int)(ub & 0x3FFu);
        // loss term: ||e||^2 - 2<e,z> of designated row (||z||^2 via zsq)
        lsum += __uint_as_float(ub & 0xFFFFFC00u);
    }
    // wave-local LDS exchange: writes above, reads below, same wave only.
    asm volatile("s_waitcnt lgkmcnt(0)" ::: "memory");

    // Epilogue: gather exact fp32 codebook rows, coalesced float4 store.
    const float4* cb4 = (const float4*)cb;
    float4* out4 = (float4*)out;
    #pragma unroll 4
    for (int g = 0; g < 8; ++g) {
        const int rr = g * 4 + quad;                 // 4 rows per iteration
        const int idx = s_idx[wave * 32 + rr];       // broadcast read
        float4 e = cb4[idx * 16 + lrow];
        out4[(size_t)(r0 + rr) * 16 + lrow] = e;
    }

    // Loss: wave reduce -> LDS -> one atomic per block.
    #pragma unroll
    for (int off = 32; off > 0; off >>= 1)
        lsum += __shfl_down(lsum, off, 64);
    if (lane == 0) s_red[wave] = lsum;
    __syncthreads();
    if (tid == 0) {
        float bs = 0.f;
        #pragma unroll
        for (int w = 0; w < WAVES; ++w) bs += s_red[w];
        atomicAdd(ws, bs);
        // make the loss add globally visible before the arrival counter
        asm volatile("s_waitcnt vmcnt(0)" ::: "memory");
        unsigned old = atomicAdd((unsigned*)ws + 1, 1u);
        if (old == (unsigned)(GRID - 1)) {
            float s = atomicAdd(ws, 0.0f);   // coherent read of final sum
            out[NELEM] = 1.25f * s * (1.0f / (float)NELEM);
        }
    }
}

extern "C" void kernel_launch(void* const* d_in, const int* in_sizes, int n_in,
                              void* d_out, int out_size, void* d_ws, size_t ws_size,
                              hipStream_t stream) {
    const float* z  = (const float*)d_in[0];
    const float* cb = (const float*)d_in[1];
    float* out = (float*)d_out;

    float* ws   = (float*)d_ws;                           // [0]=loss, [1]=counter
    short* cbbf = (short*)((char*)d_ws + 512);            // 128 KB bf16(-2*cb)
    float* esq  = (float*)((char*)d_ws + 512 + 131072);   // 1024 fp32

    vq_prep<<<64, 1024, 0, stream>>>(cb, cbbf, esq, ws);
    vq_main<<<GRID, 1024, 0, stream>>>(z, cb, cbbf, esq, out, ws);
}

// Round 3
// 168.021 us; speedup vs baseline: 1.1915x; 1.1915x over previous
//
#include <hip/hip_runtime.h>
#include <math.h>

// z = (64,64,64,64) fp32 -> 262144 vectors of dim 64; codebook = 1024 x 64 fp32.
constexpr int DIM  = 64;
constexpr int KCB  = 1024;
constexpr int NVEC = 262144;
constexpr long long NELEM = 16777216LL;
constexpr int WAVES   = 16;              // 1024 threads/block
constexpr int ROWS_PB = 512;             // 32 rows per wave
constexpr int GRID    = NVEC / ROWS_PB;  // 512 blocks = 2 per CU (72 KB LDS)
constexpr int KHALF   = 512;             // codewords staged per half

typedef short bf16x8 __attribute__((ext_vector_type(8)));  // 8 bf16 = 4 VGPRs
typedef float f32x4  __attribute__((ext_vector_type(4)));

// async global->LDS, 16 B per lane; LDS dest = wave-uniform base + lane*16
#define GLDS16(gp, lp) __builtin_amdgcn_global_load_lds(                      \
    (const __attribute__((address_space(1))) unsigned int*)(gp),              \
    (__attribute__((address_space(3))) unsigned int*)(lp), 16, 0, 0)

// fp32 -> bf16 round-to-nearest-even
__device__ __forceinline__ unsigned f2bfu(float f) {
    union { float f; unsigned u; } v; v.f = f;
    return (v.u + 0x7fffu + ((v.u >> 16) & 1u)) >> 16;
}

// Prep: cbbf = bf16(-2*cb) row-major, esq = ||e_k||^2, zero ws[0..1].
__global__ __launch_bounds__(1024) void vq_prep(const float* __restrict__ cb,
        short* __restrict__ cbbf, float* __restrict__ esq, float* __restrict__ ws) {
    int i = blockIdx.x * 1024 + threadIdx.x;   // 64 blocks x 1024 = 65536
    cbbf[i] = (short)f2bfu(-2.0f * cb[i]);
    if (i < KCB) {
        const float* e = cb + i * DIM;
        float s0 = 0.f, s1 = 0.f, s2 = 0.f, s3 = 0.f;
        #pragma unroll
        for (int j = 0; j < DIM; j += 4) {
            float4 v = *(const float4*)(e + j);
            s0 = fmaf(v.x, v.x, s0);
            s1 = fmaf(v.y, v.y, s1);
            s2 = fmaf(v.z, v.z, s2);
            s3 = fmaf(v.w, v.w, s3);
        }
        esq[i] = (s0 + s1) + (s2 + s3);
    }
    if (i == 0) { ws[0] = 0.f; ((unsigned*)ws)[1] = 0u; }
}

// Stage one 64 KB half-codebook via global_load_lds width=16.
// Swizzle: 16-B unit `part` of codeword `col` lands at LDS slot
// col*8 + ((part+col)&7), realized by permuting the *global source* address
// (GLDS LDS dest must be linear: wave-uniform base + lane*16).
// Offsets recomputed per call so they don't stay live across the hot loop.
__device__ __forceinline__ void stage_half(const char* gsrc, char* lbase,
                                           int wave, int lane) {
    #pragma unroll
    for (int j = 0; j < 4; ++j) {
        int s = wave * 256 + j * 64 + lane;      // 16-B slot index
        int col = s >> 3, pos = s & 7;
        int part = (pos - col) & 7;
        GLDS16(gsrc + (unsigned)((col * 8 + part) * 16),
               lbase + (unsigned)((wave * 256 + j * 64) * 16));
    }
}

// Main: fused argmin+gather+loss. 72 KB LDS + ~56 VGPR (NO launch-bounds reg
// cap: round-2's (1024,8) forced VGPR=32 -> ~70 MB spill writes, dur 110us).
// 2 blocks/CU x 16 waves = 8 waves/SIMD: one block's stage/barrier/store
// phases hide under the other block's hot loop.
__global__ __launch_bounds__(1024, 4) void vq_main(
        const float* __restrict__ z,
        const float* __restrict__ cb,
        const short* __restrict__ cbbf,
        const float* __restrict__ esq,
        float* __restrict__ out,
        float* __restrict__ ws) {

    __shared__ unsigned sB[KHALF * 32];     // 64 KB staged half-codebook
    __shared__ float    s_esq[KCB];         // 4 KB
    __shared__ int      s_idx[WAVES * 32];  // 2 KB per-wave argmin exchange
    __shared__ float    s_red[WAVES];       // block loss partials

    const int tid  = threadIdx.x;
    const int lane = tid & 63;
    const int wave = tid >> 6;
    const int quad = lane >> 4;
    const int lrow = lane & 15;
    const int r0   = blockIdx.x * ROWS_PB + wave * 32;

    const char* gB = (const char*)cbbf;
    stage_half(gB, (char*)sB, wave, lane);       // half 0, fire-and-forget

    s_esq[tid] = esq[tid];

    // A fragments: A[m=lane&15][k=quad*8+j], bf16(z); exact fp32 ||z||^2
    // partials (each lane covers 16 elems of its rows).
    bf16x8 a0[2], a1[2];
    float zsq = 0.f;
    #pragma unroll
    for (int t = 0; t < 2; ++t) {
        const float* zr = z + (size_t)(r0 + t * 16 + lrow) * DIM + quad * 8;
        float4 p0 = *(const float4*)(zr);
        float4 p1 = *(const float4*)(zr + 4);
        float4 p2 = *(const float4*)(zr + 32);
        float4 p3 = *(const float4*)(zr + 36);
        zsq = fmaf(p0.x, p0.x, zsq); zsq = fmaf(p0.y, p0.y, zsq);
        zsq = fmaf(p0.z, p0.z, zsq); zsq = fmaf(p0.w, p0.w, zsq);
        zsq = fmaf(p1.x, p1.x, zsq); zsq = fmaf(p1.y, p1.y, zsq);
        zsq = fmaf(p1.z, p1.z, zsq); zsq = fmaf(p1.w, p1.w, zsq);
        zsq = fmaf(p2.x, p2.x, zsq); zsq = fmaf(p2.y, p2.y, zsq);
        zsq = fmaf(p2.z, p2.z, zsq); zsq = fmaf(p2.w, p2.w, zsq);
        zsq = fmaf(p3.x, p3.x, zsq); zsq = fmaf(p3.y, p3.y, zsq);
        zsq = fmaf(p3.z, p3.z, zsq); zsq = fmaf(p3.w, p3.w, zsq);
        a0[t][0] = (short)f2bfu(p0.x); a0[t][1] = (short)f2bfu(p0.y);
        a0[t][2] = (short)f2bfu(p0.z); a0[t][3] = (short)f2bfu(p0.w);
        a0[t][4] = (short)f2bfu(p1.x); a0[t][5] = (short)f2bfu(p1.y);
        a0[t][6] = (short)f2bfu(p1.z); a0[t][7] = (short)f2bfu(p1.w);
        a1[t][0] = (short)f2bfu(p2.x); a1[t][1] = (short)f2bfu(p2.y);
        a1[t][2] = (short)f2bfu(p2.z); a1[t][3] = (short)f2bfu(p2.w);
        a1[t][4] = (short)f2bfu(p3.x); a1[t][5] = (short)f2bfu(p3.y);
        a1[t][6] = (short)f2bfu(p3.z); a1[t][7] = (short)f2bfu(p3.w);
    }

    __syncthreads();   // drains half-0 GLDS (vmcnt) + esq write

    float best[2][4];
    #pragma unroll
    for (int t = 0; t < 2; ++t)
        #pragma unroll
        for (int i = 0; i < 4; ++i) best[t][i] = INFINITY;

    const int pos0 = ((quad + lrow) & 7) * 4;       // b0: part=quad   (K 0..31)
    const int pos1 = ((quad + 4 + lrow) & 7) * 4;   // b1: part=quad+4 (K 32..63)

    for (int half = 0; half < 2; ++half) {
        const int kbase = half * KHALF;
        #pragma unroll 2
        for (int ks = 0; ks < 32; ks += 2) {
            const int row = ks * 16 + lrow;
            const unsigned* bpA = sB + row * 32;
            const unsigned* bpB = bpA + 512;         // codeword group row+16
            bf16x8 b0A = *(const bf16x8*)(bpA + pos0);
            bf16x8 b1A = *(const bf16x8*)(bpA + pos1);
            bf16x8 b0B = *(const bf16x8*)(bpB + pos0);
            bf16x8 b1B = *(const bf16x8*)(bpB + pos1);
            const float esA = s_esq[kbase + row];
            const float esB = s_esq[kbase + row + 16];
            const unsigned cvA = (unsigned)(kbase + row);
            const unsigned cvB = cvA + 16u;
            #pragma unroll
            for (int t = 0; t < 2; ++t) {
                f32x4 accA = { esA, esA, esA, esA };
                accA = __builtin_amdgcn_mfma_f32_16x16x32_bf16(a0[t], b0A, accA, 0, 0, 0);
                accA = __builtin_amdgcn_mfma_f32_16x16x32_bf16(a1[t], b1A, accA, 0, 0, 0);
                f32x4 accB = { esB, esB, esB, esB };
                accB = __builtin_amdgcn_mfma_f32_16x16x32_bf16(a0[t], b0B, accB, 0, 0, 0);
                accB = __builtin_amdgcn_mfma_f32_16x16x32_bf16(a1[t], b1B, accB, 0, 0, 0);
                #pragma unroll
                for (int i = 0; i < 4; ++i) {
                    unsigned uA = __float_as_uint(accA[i]);
                    unsigned uB = __float_as_uint(accB[i]);
                    float pkA = __uint_as_float((uA & 0xFFFFFC00u) | cvA);
                    float pkB = __uint_as_float((uB & 0xFFFFFC00u) | cvB);
                    best[t][i] = fminf(best[t][i], fminf(pkA, pkB));
                }
            }
        }
        if (half == 0) {
            __syncthreads();                         // all waves done reading
            stage_half(gB + KHALF * DIM * 2, (char*)sB, wave, lane);
            __syncthreads();                         // drains half-1 GLDS
        }
    }

    // min across the 16-lane col group (quad-local butterfly)
    #pragma unroll
    for (int t = 0; t < 2; ++t)
        #pragma unroll
        for (int i = 0; i < 4; ++i) {
            float bs = best[t][i];
            bs = fminf(bs, __shfl_xor(bs, 1, 64));
            bs = fminf(bs, __shfl_xor(bs, 2, 64));
            bs = fminf(bs, __shfl_xor(bs, 4, 64));
            bs = fminf(bs, __shfl_xor(bs, 8, 64));
            best[t][i] = bs;
        }

    // lane lrow = t*4+i (lrow<8) owns row t*16 + quad*4 + i (static select)
    float mypk = best[0][0];
    #pragma unroll
    for (int t = 0; t < 2; ++t)
        #pragma unroll
        for (int i = 0; i < 4; ++i)
            if (lrow == t * 4 + i) mypk = best[t][i];

    const unsigned ub = __float_as_uint(mypk);
    float lsum = zsq;
    if (lrow < 8) {
        s_idx[wave * 32 + (lrow >> 2) * 16 + quad * 4 + (lrow & 3)] =
            (int)(ub & 0x3FFu);
        // loss term: ||e||^2 - 2<e,z> of designated row (||z||^2 via zsq)
        lsum += __uint_as_float(ub & 0xFFFFFC00u);
    }
    // wave-local LDS exchange: writes above, reads below, same wave only.
    asm volatile("s_waitcnt lgkmcnt(0)" ::: "memory");

    // Epilogue: gather exact fp32 codebook rows, coalesced float4 store.
    const float4* cb4 = (const float4*)cb;
    float4* out4 = (float4*)out;
    #pragma unroll 4
    for (int g = 0; g < 8; ++g) {
        const int rr = g * 4 + quad;                 // 4 rows per iteration
        const int idx = s_idx[wave * 32 + rr];       // broadcast read
        float4 e = cb4[idx * 16 + lrow];
        out4[(size_t)(r0 + rr) * 16 + lrow] = e;
    }

    // Loss: wave reduce -> LDS -> one atomic per block.
    #pragma unroll
    for (int off = 32; off > 0; off >>= 1)
        lsum += __shfl_down(lsum, off, 64);
    if (lane == 0) s_red[wave] = lsum;
    __syncthreads();
    if (tid == 0) {
        float bs = 0.f;
        #pragma unroll
        for (int w = 0; w < WAVES; ++w) bs += s_red[w];
        atomicAdd(ws, bs);
        // make the loss add globally visible before the arrival counter
        asm volatile("s_waitcnt vmcnt(0)" ::: "memory");
        unsigned old = atomicAdd((unsigned*)ws + 1, 1u);
        if (old == (unsigned)(GRID - 1)) {
            float s = atomicAdd(ws, 0.0f);   // coherent read of final sum
            out[NELEM] = 1.25f * s * (1.0f / (float)NELEM);
        }
    }
}

extern "C" void kernel_launch(void* const* d_in, const int* in_sizes, int n_in,
                              void* d_out, int out_size, void* d_ws, size_t ws_size,
                              hipStream_t stream) {
    const float* z  = (const float*)d_in[0];
    const float* cb = (const float*)d_in[1];
    float* out = (float*)d_out;

    float* ws   = (float*)d_ws;                           // [0]=loss, [1]=counter
    short* cbbf = (short*)((char*)d_ws + 512);            // 128 KB bf16(-2*cb)
    float* esq  = (float*)((char*)d_ws + 512 + 131072);   // 1024 fp32

    vq_prep<<<64, 1024, 0, stream>>>(cb, cbbf, esq, ws);
    vq_main<<<GRID, 1024, 0, stream>>>(z, cb, cbbf, esq, out, ws);
}

// Round 4
// 155.853 us; speedup vs baseline: 1.2846x; 1.0781x over previous
//
#include <hip/hip_runtime.h>
#include <math.h>

// z = (64,64,64,64) fp32 -> 262144 vectors of dim 64; codebook = 1024 x 64 fp32.
constexpr int DIM  = 64;
constexpr int KCB  = 1024;
constexpr int NVEC = 262144;
constexpr long long NELEM = 16777216LL;
constexpr int WAVES   = 16;              // 1024 threads/block
constexpr int ROWS_PW = 64;              // rows per wave (4 MFMA tiles)
constexpr int GRID    = NVEC / (WAVES * ROWS_PW);  // 256 blocks = 1 per CU

typedef short bf16x8 __attribute__((ext_vector_type(8)));  // 8 bf16 = 4 VGPRs
typedef float f32x4  __attribute__((ext_vector_type(4)));

// fp32 -> bf16 round-to-nearest-even, result in low 16 bits
__device__ __forceinline__ unsigned f2bfu(float f) {
    union { float f; unsigned u; } v; v.f = f;
    return (v.u + 0x7fffu + ((v.u >> 16) & 1u)) >> 16;
}

// Single dispatch, one block per CU, ONE mid-kernel barrier.
// Whole codebook lives in LDS as bf16(-2*cb), XOR-swizzled (16-B unit `part`
// of codeword `col` at slot col*8+((part+col)&7) => ds_read_b128 fragments
// <=2-way conflict-free). Rows processed as 2 groups of 32/wave: group-0
// stores are fire-and-forget and drain under group-1's MFMA/min loop.
// Loss comes from the tracked packed min distance (||z||^2 + (||e||^2-2<e,z>)).
__global__ __launch_bounds__(1024, 4) void vq_fused(
        const float* __restrict__ z,
        const float* __restrict__ cb,
        float* __restrict__ out,
        float* __restrict__ ws) {

    __shared__ unsigned sB[KCB * 32];       // 128 KB swizzled bf16(-2*cb)
    __shared__ float    s_esq[KCB];         // 4 KB ||e_k||^2
    __shared__ int      s_idx[WAVES * 32];  // 2 KB per-wave argmin exchange
    __shared__ float    s_red[WAVES];       // block loss partials

    const int tid  = threadIdx.x;
    const int lane = tid & 63;
    const int wave = tid >> 6;
    const int quad = lane >> 4;
    const int lrow = lane & 15;
    const int r0   = blockIdx.x * (WAVES * ROWS_PW) + wave * ROWS_PW;

    // ---- build B in LDS (swizzled) + esq, straight from fp32 cb ----
    // slot s = c*1024 + tid; col = s>>3, jj = s&7, part = (jj-col)&7.
    // 8 consecutive lanes hold the 8 parts of one codeword -> esq via 3 xors.
    {
        const int col_l = tid >> 3;            // 0..127 within chunk
        const int jj    = tid & 7;
        const int part  = (jj - col_l) & 7;
        const float* src = cb + col_l * DIM + part * 8;
        char* dst = (char*)sB + tid * 16;
        #pragma unroll
        for (int c = 0; c < 8; ++c) {          // chunk c: codewords c*128..
            float4 v0 = *(const float4*)(src + c * 8192);
            float4 v1 = *(const float4*)(src + c * 8192 + 4);
            float es = v0.x * v0.x;
            es = fmaf(v0.y, v0.y, es);
            es = fmaf(v0.z, v0.z, es);
            es = fmaf(v0.w, v0.w, es);
            es = fmaf(v1.x, v1.x, es);
            es = fmaf(v1.y, v1.y, es);
            es = fmaf(v1.z, v1.z, es);
            es = fmaf(v1.w, v1.w, es);
            es += __shfl_xor(es, 1, 64);
            es += __shfl_xor(es, 2, 64);
            es += __shfl_xor(es, 4, 64);
            if (jj == 0) s_esq[c * 128 + col_l] = es;
            uint4 w;
            w.x = f2bfu(-2.f * v0.x) | (f2bfu(-2.f * v0.y) << 16);
            w.y = f2bfu(-2.f * v0.z) | (f2bfu(-2.f * v0.w) << 16);
            w.z = f2bfu(-2.f * v1.x) | (f2bfu(-2.f * v1.y) << 16);
            w.w = f2bfu(-2.f * v1.z) | (f2bfu(-2.f * v1.w) << 16);
            *(uint4*)(dst + c * 16384) = w;
        }
    }

    // ---- A fragments for all 4 tiles (64 rows/wave): A[m=lrow][k=quad*8+j],
    //      bf16(z); exact fp32 ||z||^2 partials across the lane's 16 elems ----
    bf16x8 a0[4], a1[4];
    float zsq = 0.f;
    #pragma unroll
    for (int t = 0; t < 4; ++t) {
        const float* zr = z + (size_t)(r0 + t * 16 + lrow) * DIM + quad * 8;
        float4 p0 = *(const float4*)(zr);
        float4 p1 = *(const float4*)(zr + 4);
        float4 p2 = *(const float4*)(zr + 32);
        float4 p3 = *(const float4*)(zr + 36);
        zsq = fmaf(p0.x, p0.x, zsq); zsq = fmaf(p0.y, p0.y, zsq);
        zsq = fmaf(p0.z, p0.z, zsq); zsq = fmaf(p0.w, p0.w, zsq);
        zsq = fmaf(p1.x, p1.x, zsq); zsq = fmaf(p1.y, p1.y, zsq);
        zsq = fmaf(p1.z, p1.z, zsq); zsq = fmaf(p1.w, p1.w, zsq);
        zsq = fmaf(p2.x, p2.x, zsq); zsq = fmaf(p2.y, p2.y, zsq);
        zsq = fmaf(p2.z, p2.z, zsq); zsq = fmaf(p2.w, p2.w, zsq);
        zsq = fmaf(p3.x, p3.x, zsq); zsq = fmaf(p3.y, p3.y, zsq);
        zsq = fmaf(p3.z, p3.z, zsq); zsq = fmaf(p3.w, p3.w, zsq);
        a0[t][0] = (short)f2bfu(p0.x); a0[t][1] = (short)f2bfu(p0.y);
        a0[t][2] = (short)f2bfu(p0.z); a0[t][3] = (short)f2bfu(p0.w);
        a0[t][4] = (short)f2bfu(p1.x); a0[t][5] = (short)f2bfu(p1.y);
        a0[t][6] = (short)f2bfu(p1.z); a0[t][7] = (short)f2bfu(p1.w);
        a1[t][0] = (short)f2bfu(p2.x); a1[t][1] = (short)f2bfu(p2.y);
        a1[t][2] = (short)f2bfu(p2.z); a1[t][3] = (short)f2bfu(p2.w);
        a1[t][4] = (short)f2bfu(p3.x); a1[t][5] = (short)f2bfu(p3.y);
        a1[t][6] = (short)f2bfu(p3.z); a1[t][7] = (short)f2bfu(p3.w);
    }

    __syncthreads();   // the ONLY staging barrier; waves free-run after this

    const int pos0 = ((quad + lrow) & 7) * 4;       // b0: part=quad   (K 0..31)
    const int pos1 = ((quad + 4 + lrow) & 7) * 4;   // b1: part=quad+4 (K 32..63)
    const int base = lrow * 32;
    const float4* cb4 = (const float4*)cb;
    float4* out4 = (float4*)out;
    float lsum = zsq;

    #pragma unroll
    for (int grp = 0; grp < 2; ++grp) {             // 2 groups of 32 rows/wave
        float best[2][4];
        #pragma unroll
        for (int tt = 0; tt < 2; ++tt)
            #pragma unroll
            for (int i = 0; i < 4; ++i) best[tt][i] = INFINITY;

        #pragma unroll 2
        for (int ks = 0; ks < 64; ks += 2) {
            const unsigned* bpA = sB + ks * 512 + base;
            const unsigned* bpB = bpA + 512;
            bf16x8 b0A = *(const bf16x8*)(bpA + pos0);
            bf16x8 b1A = *(const bf16x8*)(bpA + pos1);
            bf16x8 b0B = *(const bf16x8*)(bpB + pos0);
            bf16x8 b1B = *(const bf16x8*)(bpB + pos1);
            const float esA = s_esq[ks * 16 + lrow];
            const float esB = s_esq[ks * 16 + 16 + lrow];
            const unsigned cvA = (unsigned)(ks * 16 + lrow);
            const unsigned cvB = cvA + 16u;
            #pragma unroll
            for (int tt = 0; tt < 2; ++tt) {
                f32x4 accA = { esA, esA, esA, esA };
                accA = __builtin_amdgcn_mfma_f32_16x16x32_bf16(a0[grp * 2 + tt], b0A, accA, 0, 0, 0);
                accA = __builtin_amdgcn_mfma_f32_16x16x32_bf16(a1[grp * 2 + tt], b1A, accA, 0, 0, 0);
                f32x4 accB = { esB, esB, esB, esB };
                accB = __builtin_amdgcn_mfma_f32_16x16x32_bf16(a0[grp * 2 + tt], b0B, accB, 0, 0, 0);
                accB = __builtin_amdgcn_mfma_f32_16x16x32_bf16(a1[grp * 2 + tt], b1B, accB, 0, 0, 0);
                #pragma unroll
                for (int i = 0; i < 4; ++i) {
                    unsigned uA = __float_as_uint(accA[i]);
                    unsigned uB = __float_as_uint(accB[i]);
                    float pkA = __uint_as_float((uA & 0xFFFFFC00u) | cvA);
                    float pkB = __uint_as_float((uB & 0xFFFFFC00u) | cvB);
                    best[tt][i] = fminf(best[tt][i], fminf(pkA, pkB));
                }
            }
        }

        // min across the 16-lane col group (butterfly)
        #pragma unroll
        for (int tt = 0; tt < 2; ++tt)
            #pragma unroll
            for (int i = 0; i < 4; ++i) {
                float bs = best[tt][i];
                bs = fminf(bs, __shfl_xor(bs, 1, 64));
                bs = fminf(bs, __shfl_xor(bs, 2, 64));
                bs = fminf(bs, __shfl_xor(bs, 4, 64));
                bs = fminf(bs, __shfl_xor(bs, 8, 64));
                best[tt][i] = bs;
            }

        // lane lrow = tt*4+i (lrow<8) owns row tt*16 + quad*4 + i (static sel)
        float mypk = best[0][0];
        #pragma unroll
        for (int tt = 0; tt < 2; ++tt)
            #pragma unroll
            for (int i = 0; i < 4; ++i)
                if (lrow == tt * 4 + i) mypk = best[tt][i];

        const unsigned ub = __float_as_uint(mypk);
        if (lrow < 8) {
            s_idx[wave * 32 + (lrow >> 2) * 16 + quad * 4 + (lrow & 3)] =
                (int)(ub & 0x3FFu);
            // loss term: ||e||^2 - 2<e,z> of the owned row
            lsum += __uint_as_float(ub & 0xFFFFFC00u);
        }
        // wave-local LDS exchange: same wave writes then reads; fence lgkm.
        asm volatile("s_waitcnt lgkmcnt(0)" ::: "memory");

        // gather exact fp32 codebook rows; stores fire-and-forget (drain
        // overlaps the next group's hot loop).
        #pragma unroll 4
        for (int g = 0; g < 8; ++g) {
            const int rr = g * 4 + quad;                 // 4 rows / iteration
            const int idx = s_idx[wave * 32 + rr];       // broadcast read
            float4 e = cb4[idx * 16 + lrow];
            out4[(size_t)(r0 + grp * 32 + rr) * 16 + lrow] = e;
        }
    }

    // ---- loss: wave reduce -> LDS -> one atomic per block ----
    #pragma unroll
    for (int off = 32; off > 0; off >>= 1)
        lsum += __shfl_down(lsum, off, 64);
    if (lane == 0) s_red[wave] = lsum;
    __syncthreads();
    if (tid == 0) {
        float bs = 0.f;
        #pragma unroll
        for (int w = 0; w < WAVES; ++w) bs += s_red[w];
        atomicAdd(ws, bs);
        // make the loss add globally visible before the arrival counter
        asm volatile("s_waitcnt vmcnt(0)" ::: "memory");
        unsigned old = atomicAdd((unsigned*)ws + 1, 1u);
        if (old == (unsigned)(GRID - 1)) {
            float s = atomicAdd(ws, 0.0f);   // coherent read of final sum
            out[NELEM] = 1.25f * s * (1.0f / (float)NELEM);
        }
    }
}

extern "C" void kernel_launch(void* const* d_in, const int* in_sizes, int n_in,
                              void* d_out, int out_size, void* d_ws, size_t ws_size,
                              hipStream_t stream) {
    const float* z  = (const float*)d_in[0];
    const float* cb = (const float*)d_in[1];
    float* out = (float*)d_out;
    float* ws  = (float*)d_ws;   // [0]=loss accum, [1]=block counter

    hipMemsetAsync(ws, 0, 8, stream);
    vq_fused<<<GRID, 1024, 0, stream>>>(z, cb, out, ws);
}

// Round 5
// 152.044 us; speedup vs baseline: 1.3168x; 1.0250x over previous
//
#include <hip/hip_runtime.h>
#include <math.h>

// z = (64,64,64,64) fp32 -> 262144 vectors of dim 64; codebook = 1024 x 64 fp32.
constexpr int DIM  = 64;
constexpr int KCB  = 1024;
constexpr int NVEC = 262144;
constexpr long long NELEM = 16777216LL;
constexpr int WAVES   = 16;              // 1024 threads/block
constexpr int ROWS_PW = 64;              // rows per wave (4 MFMA tiles)
constexpr int GRID    = NVEC / (WAVES * ROWS_PW);  // 256 blocks = 1 per CU

typedef short bf16x8 __attribute__((ext_vector_type(8)));  // 8 bf16 = 4 VGPRs
typedef float f32x4  __attribute__((ext_vector_type(4)));

// fp32 -> bf16 round-to-nearest-even, result in low 16 bits
__device__ __forceinline__ unsigned f2bfu(float f) {
    union { float f; unsigned u; } v; v.f = f;
    return (v.u + 0x7fffu + ((v.u >> 16) & 1u)) >> 16;
}

// (u & 0xFFFFFC00) | cv in ONE VALU op (compiler can't prove cv<1024).
__device__ __forceinline__ float pack_dc(unsigned u, unsigned cv, unsigned msk) {
    unsigned r;
    asm("v_bfi_b32 %0, %1, %2, %3" : "=v"(r) : "v"(msk), "v"(u), "v"(cv));
    return __uint_as_float(r);
}

// Single dispatch, one block per CU, ONE barrier. Whole codebook in LDS as
// bf16(-2*cb), XOR-swizzled (16-B unit `part` of codeword `col` at slot
// col*8+((part+col)&7) => ds_read_b128 fragments <=2-way, free).
// ONE 64-row scan per wave: each 4xds_read_b128 B-bundle feeds 16 MFMA
// (round-4 fed only 8 and scanned twice -> 2x LDS traffic, half the
// latency-hiding). Loss from the tracked packed min distance:
// ||z-e||^2 = ||z||^2 + (||e||^2 - 2<e,z>).
__global__ __launch_bounds__(1024, 4) void vq_fused(
        const float* __restrict__ z,
        const float* __restrict__ cb,
        float* __restrict__ out,
        float* __restrict__ ws) {

    __shared__ unsigned sB[KCB * 32];       // 128 KB swizzled bf16(-2*cb)
    __shared__ float    s_esq[KCB];         // 4 KB ||e_k||^2
    __shared__ int      s_idx[WAVES * 64];  // 4 KB per-wave argmin exchange
    __shared__ float    s_red[WAVES];       // block loss partials

    const int tid  = threadIdx.x;
    const int lane = tid & 63;
    const int wave = tid >> 6;
    const int quad = lane >> 4;
    const int lrow = lane & 15;
    const int r0   = blockIdx.x * (WAVES * ROWS_PW) + wave * ROWS_PW;

    // ---- A fragments FIRST (z is the cold per-block HBM read; its latency
    //      hides under the cb staging VALU below). A[m=lrow][k=quad*8+j],
    //      bf16(z); exact fp32 ||z||^2 partials (16 elems/lane/row-set) ----
    bf16x8 a0[4], a1[4];
    float zsq = 0.f;
    #pragma unroll
    for (int t = 0; t < 4; ++t) {
        const float* zr = z + (size_t)(r0 + t * 16 + lrow) * DIM + quad * 8;
        float4 p0 = *(const float4*)(zr);
        float4 p1 = *(const float4*)(zr + 4);
        float4 p2 = *(const float4*)(zr + 32);
        float4 p3 = *(const float4*)(zr + 36);
        zsq = fmaf(p0.x, p0.x, zsq); zsq = fmaf(p0.y, p0.y, zsq);
        zsq = fmaf(p0.z, p0.z, zsq); zsq = fmaf(p0.w, p0.w, zsq);
        zsq = fmaf(p1.x, p1.x, zsq); zsq = fmaf(p1.y, p1.y, zsq);
        zsq = fmaf(p1.z, p1.z, zsq); zsq = fmaf(p1.w, p1.w, zsq);
        zsq = fmaf(p2.x, p2.x, zsq); zsq = fmaf(p2.y, p2.y, zsq);
        zsq = fmaf(p2.z, p2.z, zsq); zsq = fmaf(p2.w, p2.w, zsq);
        zsq = fmaf(p3.x, p3.x, zsq); zsq = fmaf(p3.y, p3.y, zsq);
        zsq = fmaf(p3.z, p3.z, zsq); zsq = fmaf(p3.w, p3.w, zsq);
        a0[t][0] = (short)f2bfu(p0.x); a0[t][1] = (short)f2bfu(p0.y);
        a0[t][2] = (short)f2bfu(p0.z); a0[t][3] = (short)f2bfu(p0.w);
        a0[t][4] = (short)f2bfu(p1.x); a0[t][5] = (short)f2bfu(p1.y);
        a0[t][6] = (short)f2bfu(p1.z); a0[t][7] = (short)f2bfu(p1.w);
        a1[t][0] = (short)f2bfu(p2.x); a1[t][1] = (short)f2bfu(p2.y);
        a1[t][2] = (short)f2bfu(p2.z); a1[t][3] = (short)f2bfu(p2.w);
        a1[t][4] = (short)f2bfu(p3.x); a1[t][5] = (short)f2bfu(p3.y);
        a1[t][6] = (short)f2bfu(p3.z); a1[t][7] = (short)f2bfu(p3.w);
    }

    // ---- build B in LDS (swizzled) + esq, straight from fp32 cb ----
    // slot s = c*1024 + tid; col = s>>3, jj = s&7, part = (jj-col)&7.
    // 8 consecutive lanes hold the 8 parts of one codeword -> esq via 3 xors.
    {
        const int col_l = tid >> 3;            // 0..127 within chunk
        const int jj    = tid & 7;
        const int part  = (jj - col_l) & 7;
        const float* src = cb + col_l * DIM + part * 8;
        char* dst = (char*)sB + tid * 16;
        #pragma unroll
        for (int c = 0; c < 8; ++c) {          // chunk c: codewords c*128..
            float4 v0 = *(const float4*)(src + c * 8192);
            float4 v1 = *(const float4*)(src + c * 8192 + 4);
            float es = v0.x * v0.x;
            es = fmaf(v0.y, v0.y, es);
            es = fmaf(v0.z, v0.z, es);
            es = fmaf(v0.w, v0.w, es);
            es = fmaf(v1.x, v1.x, es);
            es = fmaf(v1.y, v1.y, es);
            es = fmaf(v1.z, v1.z, es);
            es = fmaf(v1.w, v1.w, es);
            es += __shfl_xor(es, 1, 64);
            es += __shfl_xor(es, 2, 64);
            es += __shfl_xor(es, 4, 64);
            if (jj == 0) s_esq[c * 128 + col_l] = es;
            uint4 w;
            w.x = f2bfu(-2.f * v0.x) | (f2bfu(-2.f * v0.y) << 16);
            w.y = f2bfu(-2.f * v0.z) | (f2bfu(-2.f * v0.w) << 16);
            w.z = f2bfu(-2.f * v1.x) | (f2bfu(-2.f * v1.y) << 16);
            w.w = f2bfu(-2.f * v1.z) | (f2bfu(-2.f * v1.w) << 16);
            *(uint4*)(dst + c * 16384) = w;
        }
    }

    __syncthreads();   // the ONLY staging barrier; waves free-run after this

    const int pos0 = ((quad + lrow) & 7) * 4;       // b0: part=quad   (K 0..31)
    const int pos1 = ((quad + 4 + lrow) & 7) * 4;   // b1: part=quad+4 (K 32..63)
    const int base = lrow * 32;
    const unsigned msk = 0xFFFFFC00u;

    float best[4][4];
    #pragma unroll
    for (int t = 0; t < 4; ++t)
        #pragma unroll
        for (int i = 0; i < 4; ++i) best[t][i] = INFINITY;

    // ---- single scan: 32 iters x (4 ds_read_b128 -> 16 MFMA -> min-track)
    #pragma unroll 2
    for (int ks = 0; ks < 64; ks += 2) {
        const unsigned* bpA = sB + ks * 512 + base;
        const unsigned* bpB = bpA + 512;
        bf16x8 b0A = *(const bf16x8*)(bpA + pos0);
        bf16x8 b1A = *(const bf16x8*)(bpA + pos1);
        bf16x8 b0B = *(const bf16x8*)(bpB + pos0);
        bf16x8 b1B = *(const bf16x8*)(bpB + pos1);
        const float esA = s_esq[ks * 16 + lrow];
        const float esB = s_esq[ks * 16 + 16 + lrow];
        const unsigned cvA = (unsigned)(ks * 16 + lrow);
        const unsigned cvB = cvA + 16u;
        f32x4 accA[4], accB[4];
        __builtin_amdgcn_s_setprio(1);
        #pragma unroll
        for (int t = 0; t < 4; ++t) {
            f32x4 aA = { esA, esA, esA, esA };   // C col = lane&15 -> ||e||^2
            aA = __builtin_amdgcn_mfma_f32_16x16x32_bf16(a0[t], b0A, aA, 0, 0, 0);
            aA = __builtin_amdgcn_mfma_f32_16x16x32_bf16(a1[t], b1A, aA, 0, 0, 0);
            accA[t] = aA;
            f32x4 aB = { esB, esB, esB, esB };
            aB = __builtin_amdgcn_mfma_f32_16x16x32_bf16(a0[t], b0B, aB, 0, 0, 0);
            aB = __builtin_amdgcn_mfma_f32_16x16x32_bf16(a1[t], b1B, aB, 0, 0, 0);
            accB[t] = aB;
        }
        __builtin_amdgcn_s_setprio(0);
        #pragma unroll
        for (int t = 0; t < 4; ++t)
            #pragma unroll
            for (int i = 0; i < 4; ++i) {
                float pkA = pack_dc(__float_as_uint(accA[t][i]), cvA, msk);
                float pkB = pack_dc(__float_as_uint(accB[t][i]), cvB, msk);
                best[t][i] = fminf(best[t][i], fminf(pkA, pkB));
            }
    }

    // ---- min across the 16-lane col group (butterfly) ----
    #pragma unroll
    for (int t = 0; t < 4; ++t)
        #pragma unroll
        for (int i = 0; i < 4; ++i) {
            float bs = best[t][i];
            bs = fminf(bs, __shfl_xor(bs, 1, 64));
            bs = fminf(bs, __shfl_xor(bs, 2, 64));
            bs = fminf(bs, __shfl_xor(bs, 4, 64));
            bs = fminf(bs, __shfl_xor(bs, 8, 64));
            best[t][i] = bs;
        }

    // lane lrow owns (t=lrow>>2, i=lrow&3) -> row t*16 + quad*4 + i.
    // All 16 lanes of each quad own exactly one row: no divergence.
    float mypk = best[0][0];
    #pragma unroll
    for (int t = 0; t < 4; ++t)
        #pragma unroll
        for (int i = 0; i < 4; ++i)
            if (lrow == t * 4 + i) mypk = best[t][i];

    const unsigned ub = __float_as_uint(mypk);
    s_idx[wave * 64 + (lrow >> 2) * 16 + quad * 4 + (lrow & 3)] =
        (int)(ub & 0x3FFu);
    // loss: ||z||^2 partial + (||e||^2 - 2<e,z>) of the owned row
    float lsum = zsq + __uint_as_float(ub & msk);

    // wave-local LDS exchange: same wave writes then reads; fence lgkm only.
    asm volatile("s_waitcnt lgkmcnt(0)" ::: "memory");

    // ---- epilogue: gather exact fp32 codebook rows, coalesced store ----
    const float4* cb4 = (const float4*)cb;
    float4* out4 = (float4*)out;
    #pragma unroll 4
    for (int g = 0; g < 16; ++g) {
        const int rr = g * 4 + quad;                 // 4 rows / iteration
        const int idx = s_idx[wave * 64 + rr];       // broadcast read
        float4 e = cb4[idx * 16 + lrow];
        out4[(size_t)(r0 + rr) * 16 + lrow] = e;
    }

    // ---- loss: wave reduce -> LDS -> one atomic per block ----
    #pragma unroll
    for (int off = 32; off > 0; off >>= 1)
        lsum += __shfl_down(lsum, off, 64);
    if (lane == 0) s_red[wave] = lsum;
    __syncthreads();
    if (tid == 0) {
        float bs = 0.f;
        #pragma unroll
        for (int w = 0; w < WAVES; ++w) bs += s_red[w];
        atomicAdd(ws, bs);
        // make the loss add globally visible before the arrival counter
        asm volatile("s_waitcnt vmcnt(0)" ::: "memory");
        unsigned old = atomicAdd((unsigned*)ws + 1, 1u);
        if (old == (unsigned)(GRID - 1)) {
            float s = atomicAdd(ws, 0.0f);   // coherent read of final sum
            out[NELEM] = 1.25f * s * (1.0f / (float)NELEM);
        }
    }
}

extern "C" void kernel_launch(void* const* d_in, const int* in_sizes, int n_in,
                              void* d_out, int out_size, void* d_ws, size_t ws_size,
                              hipStream_t stream) {
    const float* z  = (const float*)d_in[0];
    const float* cb = (const float*)d_in[1];
    float* out = (float*)d_out;
    float* ws  = (float*)d_ws;   // [0]=loss accum, [1]=block counter

    hipMemsetAsync(ws, 0, 8, stream);
    vq_fused<<<GRID, 1024, 0, stream>>>(z, cb, out, ws);
}